// Round 1
// baseline (156.456 us; speedup 1.0000x reference)
//
#include <hip/hip_runtime.h>
#include <hip/hip_bf16.h>

typedef float  f32x4  __attribute__((ext_vector_type(4)));
typedef short  bf16x8 __attribute__((ext_vector_type(8)));

__device__ __forceinline__ short f2bf(float f) {
    union { __hip_bfloat16 h; short s; } u;
    u.h = __float2bfloat16(f);
    return u.s;
}

// ---------------- K1: g[b,c] = mean_{hw} x[b,c,hw] ----------------
__global__ __launch_bounds__(256) void reduce_g_kernel(const float* __restrict__ x,
                                                       float* __restrict__ g) {
    int bc = blockIdx.x;                      // b*256 + c
    const float* xp = x + (size_t)bc * 4096;
    float sum = 0.f;
    #pragma unroll
    for (int it = 0; it < 4; ++it) {
        float4 v = *reinterpret_cast<const float4*>(xp + it * 1024 + threadIdx.x * 4);
        sum += v.x + v.y + v.z + v.w;
    }
    #pragma unroll
    for (int off = 32; off; off >>= 1) sum += __shfl_down(sum, off, 64);
    __shared__ float warp_s[4];
    if ((threadIdx.x & 63) == 0) warp_s[threadIdx.x >> 6] = sum;
    __syncthreads();
    if (threadIdx.x == 0)
        g[bc] = (warp_s[0] + warp_s[1] + warp_s[2] + warp_s[3]) * (1.0f / 4096.0f);
}

// ---------------- K2: s, t, q and w2l->bf16 ----------------
__global__ __launch_bounds__(256) void prep_kernel(
    const float* __restrict__ g, const float* __restrict__ w1l,
    const float* __restrict__ w1g1, const float* __restrict__ w1g2,
    const float* __restrict__ w2l, const float* __restrict__ w2g,
    float* __restrict__ s_out, float* __restrict__ t_out,
    float* __restrict__ q_out, short* __restrict__ w2l_bf) {
    int b = blockIdx.x;
    int tid = threadIdx.x;
    if (b == 32) {  // convert w2l (256x256) to bf16
        for (int it = 0; it < 256; ++it) {
            int e = it * 256 + tid;
            w2l_bf[e] = f2bf(w2l[e]);
        }
        return;
    }
    __shared__ float gs[256];
    __shared__ float zs[8];
    __shared__ float ss[256];
    __shared__ float red[4];
    gs[tid] = g[b * 256 + tid];
    __syncthreads();
    if (tid < 8) {  // z[g] = sum_i gg[b,g,i]*w1g1[g,i]
        float z = 0.f;
        for (int i = 0; i < 32; ++i) z += gs[tid * 32 + i] * w1g1[tid * 32 + i];
        zs[tid] = z;
    }
    __syncthreads();
    int grp = tid >> 5, o = tid & 31;
    float local = 0.f;
    #pragma unroll 4
    for (int i = 0; i < 32; ++i) local += gs[grp * 32 + i] * w1l[grp * 1024 + o * 32 + i];
    float glob = 0.f;
    #pragma unroll
    for (int gg = 0; gg < 8; ++gg) glob += zs[gg] * w1g2[tid * 8 + gg];
    float sv = 1.0f / (1.0f + expf(-(local + glob)));
    ss[tid] = sv;
    s_out[b * 256 + tid] = sv;
    // t[b] = sum_c s*w2g
    float tv = sv * w2g[tid];
    #pragma unroll
    for (int off = 32; off; off >>= 1) tv += __shfl_down(tv, off, 64);
    if ((tid & 63) == 0) red[tid >> 6] = tv;
    __syncthreads();
    float tb = red[0] + red[1] + red[2] + red[3];
    if (tid == 0) t_out[b] = tb;
    // q[b,i] = (1/256) sum_o s[o]*w2l[o,i] + t
    float v = 0.f;
    for (int o2 = 0; o2 < 256; ++o2) v += ss[o2] * w2l[o2 * 256 + tid];
    q_out[b * 256 + tid] = v * (1.0f / 256.0f) + tb;
}

// ---------------- K3: cmap0[b,p] = q[b,:]·x[b,:,p], xsum[b,p] ----------------
__global__ __launch_bounds__(256) void cmap0_kernel(const float* __restrict__ x,
                                                    const float* __restrict__ q,
                                                    float* __restrict__ cmap0,
                                                    float* __restrict__ xsum) {
    int b = blockIdx.y;
    int p = blockIdx.x * 512 + threadIdx.x * 2;
    __shared__ float qs[256];
    qs[threadIdx.x] = q[b * 256 + threadIdx.x];
    __syncthreads();
    const float* xb = x + (size_t)b * 256 * 4096;
    float a0 = 0.f, a1 = 0.f, s0 = 0.f, s1 = 0.f;
    #pragma unroll 4
    for (int i = 0; i < 256; ++i) {
        float2 v = *reinterpret_cast<const float2*>(xb + (size_t)i * 4096 + p);
        float qi = qs[i];
        a0 += qi * v.x; a1 += qi * v.y;
        s0 += v.x;      s1 += v.y;
    }
    cmap0[b * 4096 + p] = a0; cmap0[b * 4096 + p + 1] = a1;
    xsum[b * 4096 + p] = s0;  xsum[b * 4096 + p + 1] = s1;
}

// ---------------- K4: 3x3 SAME conv on (B,1,64,64), optional sigmoid ----------------
__global__ __launch_bounds__(256) void conv_kernel(const float* __restrict__ in,
                                                   const float* __restrict__ w9,
                                                   float* __restrict__ out, int do_sigmoid) {
    int b = blockIdx.x;
    float w[9];
    #pragma unroll
    for (int i = 0; i < 9; ++i) w[i] = w9[i];
    const float* ib = in + b * 4096;
    for (int it = 0; it < 16; ++it) {
        int pix = it * 256 + threadIdx.x;
        int y = pix >> 6, xx0 = pix & 63;
        float acc = 0.f;
        #pragma unroll
        for (int dy = -1; dy <= 1; ++dy) {
            #pragma unroll
            for (int dx = -1; dx <= 1; ++dx) {
                int yy = y + dy, xx = xx0 + dx;
                if (yy >= 0 && yy < 64 && xx >= 0 && xx < 64)
                    acc += ib[yy * 64 + xx] * w[(dy + 1) * 3 + (dx + 1)];
            }
        }
        if (do_sigmoid) acc = 1.0f / (1.0f + expf(-acc));
        out[b * 4096 + pix] = acc;
    }
}

// ---------------- K6: out[b,o,p] = (s[b,o]*(w2l[o,:]·x[b,:,p]) + t[b]*xsum[b,p]) * cmap[b,p]
// MFMA 16x16x32 bf16; 64x64 block tile, K-step 64, 4 waves (2x2), XOR-swizzled LDS.
#define BM 64
#define BN 64
#define BKS 64

__global__ __launch_bounds__(256) void gemm_epi_kernel(
    const float* __restrict__ x, const short* __restrict__ w2l_bf,
    const float* __restrict__ s, const float* __restrict__ t,
    const float* __restrict__ xsum, const float* __restrict__ cmap,
    float* __restrict__ out) {
    const int b  = blockIdx.z;
    const int p0 = blockIdx.x * BN;
    const int o0 = blockIdx.y * BM;
    const int tid  = threadIdx.x;
    const int lane = tid & 63;
    const int wave = tid >> 6;
    const int wm = wave >> 1, wn = wave & 1;

    __shared__ short Alds[BM * BKS];  // [o_row][k], 128B rows, 16B slots XOR-swizzled by row&7
    __shared__ short Xlds[BN * BKS];  // [p][k] (transposed), same swizzle by p&7

    f32x4 acc[2][2] = {};
    const float* xb = x + (size_t)b * 256 * 4096;

    for (int ks = 0; ks < 256; ks += BKS) {
        // ---- stage A (w2l_bf): 64 rows x 64 k = 512 x 16B slots ----
        #pragma unroll
        for (int it = 0; it < 2; ++it) {
            int v = it * 256 + tid;          // 0..511
            int row = v >> 3;
            int sl = v & 7;
            int ssl = sl ^ (row & 7);
            int4 d = *reinterpret_cast<const int4*>(w2l_bf + (size_t)(o0 + row) * 256 + ks + sl * 8);
            *reinterpret_cast<int4*>(Alds + row * 64 + ssl * 8) = d;
        }
        // ---- stage X transposed: k pairs -> packed bf16x2 writes ----
        #pragma unroll
        for (int it = 0; it < 2; ++it) {
            int v = it * 256 + tid;          // 0..511
            int kp = v >> 4;                 // 0..31 -> k = ks+2*kp, ks+2*kp+1
            int pq = v & 15;                 // p quad
            float4 va = *reinterpret_cast<const float4*>(xb + (size_t)(ks + 2 * kp) * 4096 + p0 + pq * 4);
            float4 vb = *reinterpret_cast<const float4*>(xb + (size_t)(ks + 2 * kp + 1) * 4096 + p0 + pq * 4);
            const float* pa = reinterpret_cast<const float*>(&va);
            const float* pb = reinterpret_cast<const float*>(&vb);
            #pragma unroll
            for (int e = 0; e < 4; ++e) {
                int p = pq * 4 + e;
                int byteoff = p * 128 + kp * 4;
                byteoff ^= ((p & 7) << 4);
                unsigned int packed = (unsigned int)(unsigned short)f2bf(pa[e]) |
                                      ((unsigned int)(unsigned short)f2bf(pb[e]) << 16);
                *reinterpret_cast<unsigned int*>(reinterpret_cast<char*>(Xlds) + byteoff) = packed;
            }
        }
        __syncthreads();
        // ---- compute: 2 k-chunks of 32, 2x2 16x16 tiles per wave ----
        #pragma unroll
        for (int kk = 0; kk < 2; ++kk) {
            bf16x8 af[2], bfr[2];
            #pragma unroll
            for (int sm = 0; sm < 2; ++sm) {
                int row = wm * 32 + sm * 16 + (lane & 15);
                int sl = kk * 4 + (lane >> 4);
                int ssl = sl ^ (row & 7);
                af[sm] = *reinterpret_cast<const bf16x8*>(Alds + row * 64 + ssl * 8);
            }
            #pragma unroll
            for (int sn = 0; sn < 2; ++sn) {
                int p = wn * 32 + sn * 16 + (lane & 15);
                int sl = kk * 4 + (lane >> 4);
                int ssl = sl ^ (p & 7);
                bfr[sn] = *reinterpret_cast<const bf16x8*>(Xlds + p * 64 + ssl * 8);
            }
            #pragma unroll
            for (int sm = 0; sm < 2; ++sm)
                #pragma unroll
                for (int sn = 0; sn < 2; ++sn)
                    acc[sm][sn] = __builtin_amdgcn_mfma_f32_16x16x32_bf16(af[sm], bfr[sn], acc[sm][sn], 0, 0, 0);
        }
        __syncthreads();
    }
    // ---- epilogue: out = (s*acc + t*xsum) * cmap ----
    const float tb = t[b];
    #pragma unroll
    for (int sm = 0; sm < 2; ++sm) {
        #pragma unroll
        for (int sn = 0; sn < 2; ++sn) {
            int pcol = p0 + wn * 32 + sn * 16 + (lane & 15);
            float xs = xsum[b * 4096 + pcol];
            float cm = cmap[b * 4096 + pcol];
            #pragma unroll
            for (int r = 0; r < 4; ++r) {
                int orow = o0 + wm * 32 + sm * 16 + (lane >> 4) * 4 + r;
                float sv = s[b * 256 + orow];
                float yv = sv * acc[sm][sn][r] + tb * xs;
                out[((size_t)b * 256 + orow) * 4096 + pcol] = yv * cm;
            }
        }
    }
}

extern "C" void kernel_launch(void* const* d_in, const int* in_sizes, int n_in,
                              void* d_out, int out_size, void* d_ws, size_t ws_size,
                              hipStream_t stream) {
    const float* x       = (const float*)d_in[0];
    const float* w1l     = (const float*)d_in[1];
    const float* w1g1    = (const float*)d_in[2];
    const float* w1g2    = (const float*)d_in[3];
    const float* w2l     = (const float*)d_in[4];
    const float* w2g     = (const float*)d_in[5];
    const float* conv1_w = (const float*)d_in[6];
    const float* conv2_w = (const float*)d_in[7];
    float* out = (float*)d_out;

    float* wsf   = (float*)d_ws;
    float* g     = wsf;                 // 8192
    float* s     = wsf + 8192;          // 8192
    float* t     = wsf + 16384;         // 32 (padded to 64)
    float* q     = wsf + 16448;         // 8192
    float* cmap0 = wsf + 24640;         // 131072
    float* xsum  = wsf + 155712;        // 131072
    float* sig1  = wsf + 286784;        // 131072
    float* cmap  = wsf + 417856;        // 131072
    short* w2l_bf = (short*)(wsf + 548928);  // 65536 shorts

    reduce_g_kernel<<<32 * 256, 256, 0, stream>>>(x, g);
    prep_kernel<<<33, 256, 0, stream>>>(g, w1l, w1g1, w1g2, w2l, w2g, s, t, q, w2l_bf);
    cmap0_kernel<<<dim3(8, 32), 256, 0, stream>>>(x, q, cmap0, xsum);
    conv_kernel<<<32, 256, 0, stream>>>(cmap0, conv1_w, sig1, 1);
    conv_kernel<<<32, 256, 0, stream>>>(sig1, conv2_w, cmap, 0);
    gemm_epi_kernel<<<dim3(4096 / BN, 256 / BM, 32), 256, 0, stream>>>(
        x, w2l_bf, s, t, xsum, cmap, out);
}

// Round 2
// 144.019 us; speedup vs baseline: 1.0864x; 1.0864x over previous
//
#include <hip/hip_runtime.h>
#include <hip/hip_bf16.h>

typedef float  f32x4  __attribute__((ext_vector_type(4)));
typedef short  bf16x8 __attribute__((ext_vector_type(8)));

__device__ __forceinline__ short f2bf(float f) {
    union { __hip_bfloat16 h; short s; } u;
    u.h = __float2bfloat16(f);
    return u.s;
}

__device__ __forceinline__ void gload_lds16(const void* g, void* l) {
    __builtin_amdgcn_global_load_lds(
        (const __attribute__((address_space(1))) unsigned int*)g,
        (__attribute__((address_space(3))) unsigned int*)l, 16, 0, 0);
}

// ---------------- K1: transpose x -> xt bf16 [b][p][c], partial g sums ----------------
// grid (pchunk=64, cchunk=4, b=32), 256 threads. Block tile: 64 c x 64 p.
__global__ __launch_bounds__(256) void transpose_kernel(const float* __restrict__ x,
                                                        short* __restrict__ xt,
                                                        float* __restrict__ gpart) {
    const int pchunk = blockIdx.x;
    const int c0 = blockIdx.y * 64;
    const int b  = blockIdx.z;
    const int tid = threadIdx.x;
    const int row = tid >> 2;        // c offset 0..63
    const int quad = tid & 3;        // p quarter
    const int p0 = pchunk * 64;

    __shared__ short tile[64 * 72];  // [p][c], padded rows (144B, 16B-aligned)

    const float* xr = x + ((size_t)(b * 256 + c0 + row)) * 4096 + p0 + quad * 16;
    float sum = 0.f;
    #pragma unroll
    for (int it = 0; it < 4; ++it) {
        float4 v = *reinterpret_cast<const float4*>(xr + it * 4);
        sum += v.x + v.y + v.z + v.w;
        int pb = quad * 16 + it * 4;
        tile[(pb + 0) * 72 + row] = f2bf(v.x);
        tile[(pb + 1) * 72 + row] = f2bf(v.y);
        tile[(pb + 2) * 72 + row] = f2bf(v.z);
        tile[(pb + 3) * 72 + row] = f2bf(v.w);
    }
    sum += __shfl_xor(sum, 1, 64);
    sum += __shfl_xor(sum, 2, 64);
    if (quad == 0) gpart[(size_t)(b * 256 + c0 + row) * 64 + pchunk] = sum;
    __syncthreads();
    // write out 32B per thread, coalesced per p-row
    int p = tid >> 2;
    const int4* src = reinterpret_cast<const int4*>(&tile[p * 72 + quad * 16]);
    int4* dst = reinterpret_cast<int4*>(xt + ((size_t)b * 4096 + p0 + p) * 256 + c0 + quad * 16);
    dst[0] = src[0];
    dst[1] = src[1];
}

// ---------------- K2: g-reduce, s, t, q; blocks 32..47 convert w2l->bf16 ----------------
__global__ __launch_bounds__(256) void prep_kernel(
    const float* __restrict__ gpart, const float* __restrict__ w1l,
    const float* __restrict__ w1g1, const float* __restrict__ w1g2,
    const float* __restrict__ w2l, const float* __restrict__ w2g,
    float* __restrict__ s_out, float* __restrict__ t_out,
    float* __restrict__ q_out, short* __restrict__ w2l_bf) {
    int b = blockIdx.x;
    int tid = threadIdx.x;
    if (b >= 32) {  // convert w2l (256x256) to bf16, 16 blocks
        int seg = b - 32;
        const float* src = w2l + seg * 4096;
        short* dst = w2l_bf + seg * 4096;
        #pragma unroll
        for (int it = 0; it < 4; ++it) {
            float4 v = *reinterpret_cast<const float4*>(src + it * 1024 + tid * 4);
            short4 o;
            o.x = f2bf(v.x); o.y = f2bf(v.y); o.z = f2bf(v.z); o.w = f2bf(v.w);
            *reinterpret_cast<short4*>(dst + it * 1024 + tid * 4) = o;
        }
        return;
    }
    __shared__ float gs[256];
    __shared__ float zs[8];
    __shared__ float ss[256];
    __shared__ float red[4];
    {
        const float4* gp = reinterpret_cast<const float4*>(gpart + (size_t)(b * 256 + tid) * 64);
        float acc = 0.f;
        #pragma unroll
        for (int j = 0; j < 16; ++j) { float4 v = gp[j]; acc += v.x + v.y + v.z + v.w; }
        gs[tid] = acc * (1.0f / 4096.0f);
    }
    __syncthreads();
    if (tid < 8) {
        float z = 0.f;
        for (int i = 0; i < 32; ++i) z += gs[tid * 32 + i] * w1g1[tid * 32 + i];
        zs[tid] = z;
    }
    __syncthreads();
    int grp = tid >> 5, o = tid & 31;
    float local = 0.f;
    #pragma unroll 4
    for (int i = 0; i < 32; ++i) local += gs[grp * 32 + i] * w1l[grp * 1024 + o * 32 + i];
    float glob = 0.f;
    #pragma unroll
    for (int gg = 0; gg < 8; ++gg) glob += zs[gg] * w1g2[tid * 8 + gg];
    float sv = 1.0f / (1.0f + expf(-(local + glob)));
    ss[tid] = sv;
    s_out[b * 256 + tid] = sv;
    float tv = sv * w2g[tid];
    #pragma unroll
    for (int off = 32; off; off >>= 1) tv += __shfl_down(tv, off, 64);
    if ((tid & 63) == 0) red[tid >> 6] = tv;
    __syncthreads();
    float tb = red[0] + red[1] + red[2] + red[3];
    if (tid == 0) t_out[b] = tb;
    float v = 0.f;
    for (int o2 = 0; o2 < 256; ++o2) v += ss[o2] * w2l[o2 * 256 + tid];
    q_out[b * 256 + tid] = v * (1.0f / 256.0f) + tb;
}

// ---------------- K3: cmap0[b,p] = q[b,:]·x[b,:,p], xsum[b,p] (f32 path) ----------------
__global__ __launch_bounds__(256) void cmap0_kernel(const float* __restrict__ x,
                                                    const float* __restrict__ q,
                                                    float* __restrict__ cmap0,
                                                    float* __restrict__ xsum) {
    int b = blockIdx.y;
    int p = blockIdx.x * 512 + threadIdx.x * 2;
    __shared__ float qs[256];
    qs[threadIdx.x] = q[b * 256 + threadIdx.x];
    __syncthreads();
    const float* xb = x + (size_t)b * 256 * 4096;
    float a0 = 0.f, a1 = 0.f, s0 = 0.f, s1 = 0.f;
    #pragma unroll 4
    for (int i = 0; i < 256; ++i) {
        float2 v = *reinterpret_cast<const float2*>(xb + (size_t)i * 4096 + p);
        float qi = qs[i];
        a0 += qi * v.x; a1 += qi * v.y;
        s0 += v.x;      s1 += v.y;
    }
    cmap0[b * 4096 + p] = a0; cmap0[b * 4096 + p + 1] = a1;
    xsum[b * 4096 + p] = s0;  xsum[b * 4096 + p + 1] = s1;
}

// ---------------- K4: fused conv3x3 -> sigmoid -> conv3x3, whole image in LDS ----------
__global__ __launch_bounds__(256) void convs_kernel(const float* __restrict__ in,
                                                    const float* __restrict__ w9a,
                                                    const float* __restrict__ w9b,
                                                    float* __restrict__ out) {
    int b = blockIdx.x;
    int tid = threadIdx.x;
    __shared__ float img[4096];
    __shared__ float mid[4096];
    float wa[9], wb[9];
    #pragma unroll
    for (int i = 0; i < 9; ++i) { wa[i] = w9a[i]; wb[i] = w9b[i]; }
    {
        const float4* ip = reinterpret_cast<const float4*>(in + (size_t)b * 4096);
        float4* lp = reinterpret_cast<float4*>(img);
        #pragma unroll
        for (int it = 0; it < 4; ++it) lp[it * 256 + tid] = ip[it * 256 + tid];
    }
    __syncthreads();
    #pragma unroll
    for (int it = 0; it < 16; ++it) {
        int pix = it * 256 + tid;
        int y = pix >> 6, x0 = pix & 63;
        float acc = 0.f;
        #pragma unroll
        for (int dy = -1; dy <= 1; ++dy)
            #pragma unroll
            for (int dx = -1; dx <= 1; ++dx) {
                int yy = y + dy, xx = x0 + dx;
                if (yy >= 0 && yy < 64 && xx >= 0 && xx < 64)
                    acc += img[yy * 64 + xx] * wa[(dy + 1) * 3 + (dx + 1)];
            }
        mid[pix] = 1.0f / (1.0f + expf(-acc));
    }
    __syncthreads();
    #pragma unroll
    for (int it = 0; it < 16; ++it) {
        int pix = it * 256 + tid;
        int y = pix >> 6, x0 = pix & 63;
        float acc = 0.f;
        #pragma unroll
        for (int dy = -1; dy <= 1; ++dy)
            #pragma unroll
            for (int dx = -1; dx <= 1; ++dx) {
                int yy = y + dy, xx = x0 + dx;
                if (yy >= 0 && yy < 64 && xx >= 0 && xx < 64)
                    acc += mid[yy * 64 + xx] * wb[(dy + 1) * 3 + (dx + 1)];
            }
        out[(size_t)b * 4096 + pix] = acc;
    }
}

// ---------------- K5: GEMM + epilogue. BM=256(all o) x BN=64, BK=64, 8 waves. -----------
// A = w2l_bf [o][k], X = xt [p][k] (both k-contiguous bf16) staged via global_load_lds
// width-16 with XOR swizzle applied on the SOURCE address (linear LDS dest, rule 21).
__global__ __launch_bounds__(512) void gemm_epi_kernel(
    const short* __restrict__ xt, const short* __restrict__ w2l_bf,
    const float* __restrict__ s, const float* __restrict__ t,
    const float* __restrict__ xsum, const float* __restrict__ cmap,
    float* __restrict__ out) {
    const int b  = blockIdx.z;
    const int p0 = blockIdx.x * 64;
    const int tid  = threadIdx.x;
    const int lane = tid & 63;
    const int w    = tid >> 6;          // wave 0..7
    const int wm = w >> 1, wn = w & 1;  // 4x2 wave grid: 64 o x 32 p each

    __shared__ short Alds[256 * 64];    // 32 KB: [o][k-slot swizzled]
    __shared__ short Xlds[64 * 64];     // 8 KB:  [p][k-slot swizzled]

    const int sl   = (lane & 7) ^ (lane >> 3);  // pre-swizzled source slot
    const int lrow = lane >> 3;

    f32x4 acc[4][2] = {};

    for (int ks = 0; ks < 256; ks += 64) {
        #pragma unroll
        for (int j = 0; j < 4; ++j) {
            int chunk = w * 4 + j;                 // 8 rows per chunk
            int row = chunk * 8 + lrow;
            gload_lds16(w2l_bf + (size_t)row * 256 + ks + sl * 8,
                        (char*)Alds + chunk * 1024);
        }
        {
            int prow = w * 8 + lrow;
            gload_lds16(xt + ((size_t)b * 4096 + p0 + prow) * 256 + ks + sl * 8,
                        (char*)Xlds + w * 1024);
        }
        __syncthreads();
        #pragma unroll
        for (int kk = 0; kk < 2; ++kk) {
            bf16x8 af[4], bfr[2];
            const int ss = kk * 4 + (lane >> 4);
            #pragma unroll
            for (int m = 0; m < 4; ++m) {
                int o = wm * 64 + m * 16 + (lane & 15);
                af[m] = *reinterpret_cast<const bf16x8*>(
                    (char*)Alds + o * 128 + ((ss ^ (lane & 7)) * 16));
            }
            #pragma unroll
            for (int n = 0; n < 2; ++n) {
                int p = wn * 32 + n * 16 + (lane & 15);
                bfr[n] = *reinterpret_cast<const bf16x8*>(
                    (char*)Xlds + p * 128 + ((ss ^ (lane & 7)) * 16));
            }
            #pragma unroll
            for (int m = 0; m < 4; ++m)
                #pragma unroll
                for (int n = 0; n < 2; ++n)
                    acc[m][n] = __builtin_amdgcn_mfma_f32_16x16x32_bf16(af[m], bfr[n], acc[m][n], 0, 0, 0);
        }
        __syncthreads();
    }
    const float tb = t[b];
    #pragma unroll
    for (int n = 0; n < 2; ++n) {
        int p = p0 + wn * 32 + n * 16 + (lane & 15);
        float xs = xsum[b * 4096 + p];
        float cm = cmap[b * 4096 + p];
        float txs = tb * xs;
        #pragma unroll
        for (int m = 0; m < 4; ++m) {
            #pragma unroll
            for (int r = 0; r < 4; ++r) {
                int o = wm * 64 + m * 16 + (lane >> 4) * 4 + r;
                float yv = s[b * 256 + o] * acc[m][n][r] + txs;
                out[((size_t)b * 256 + o) * 4096 + p] = yv * cm;
            }
        }
    }
}

extern "C" void kernel_launch(void* const* d_in, const int* in_sizes, int n_in,
                              void* d_out, int out_size, void* d_ws, size_t ws_size,
                              hipStream_t stream) {
    const float* x       = (const float*)d_in[0];
    const float* w1l     = (const float*)d_in[1];
    const float* w1g1    = (const float*)d_in[2];
    const float* w1g2    = (const float*)d_in[3];
    const float* w2l     = (const float*)d_in[4];
    const float* w2g     = (const float*)d_in[5];
    const float* conv1_w = (const float*)d_in[6];
    const float* conv2_w = (const float*)d_in[7];
    float* out = (float*)d_out;

    float* wsf   = (float*)d_ws;
    float* s     = wsf;                       // 8192
    float* t     = wsf + 8192;                // 64
    float* q     = wsf + 8256;                // 8192
    float* cmap0 = wsf + 16448;               // 131072
    float* xsum  = wsf + 147520;              // 131072
    float* cmap  = wsf + 278592;              // 131072
    float* gpart = wsf + 409664;              // 524288 (32*256*64)
    short* w2l_bf = (short*)(wsf + 933952);   // 65536 shorts
    short* xt     = (short*)(wsf + 966720);   // 33554432 shorts (64 MiB)

    transpose_kernel<<<dim3(64, 4, 32), 256, 0, stream>>>(x, xt, gpart);
    prep_kernel<<<48, 256, 0, stream>>>(gpart, w1l, w1g1, w1g2, w2l, w2g, s, t, q, w2l_bf);
    cmap0_kernel<<<dim3(8, 32), 256, 0, stream>>>(x, q, cmap0, xsum);
    convs_kernel<<<32, 256, 0, stream>>>(cmap0, conv1_w, conv2_w, cmap);
    gemm_epi_kernel<<<dim3(64, 1, 32), 512, 0, stream>>>(xt, w2l_bf, s, t, xsum, cmap, out);
}

// Round 3
// 141.952 us; speedup vs baseline: 1.1022x; 1.0146x over previous
//
#include <hip/hip_runtime.h>
#include <hip/hip_bf16.h>

typedef float  f32x4  __attribute__((ext_vector_type(4)));
typedef short  bf16x8 __attribute__((ext_vector_type(8)));

__device__ __forceinline__ short f2bf(float f) {
    union { __hip_bfloat16 h; short s; } u;
    u.h = __float2bfloat16(f);
    return u.s;
}

__device__ __forceinline__ void gload_lds16(const void* g, void* l) {
    __builtin_amdgcn_global_load_lds(
        (const __attribute__((address_space(1))) unsigned int*)g,
        (__attribute__((address_space(3))) unsigned int*)l, 16, 0, 0);
}

// ---------------- K1: transpose x -> xt bf16 [b][p][c], partial g sums ----------------
// Block tile: 64 c x 64 p. Thread owns a c-PAIR x 8 p. LDS: [p][32 u32] where u32 w
// holds (c=8s+2w, c=8s+2w+1) packed; 16B slot s stored at s^(p>>3) (2-way write
// conflicts = free; reads b128-aligned; global stores perfectly coalesced).
__global__ __launch_bounds__(256) void transpose_kernel(const float* __restrict__ x,
                                                        short* __restrict__ xt,
                                                        float* __restrict__ gpart) {
    const int pchunk = blockIdx.x;
    const int c0 = blockIdx.y * 64;
    const int b  = blockIdx.z;
    const int tid = threadIdx.x;
    const int cpair = tid >> 3;      // 0..31 -> c = c0 + 2*cpair + {0,1}
    const int poct  = tid & 7;       // p = poct*8 + e
    const int p0 = pchunk * 64;

    __shared__ unsigned int tile[64 * 32];   // 8 KB

    const float* rowA = x + ((size_t)(b * 256 + c0 + 2 * cpair)) * 4096 + p0 + poct * 8;
    const float* rowB = rowA + 4096;
    float av[8], bv[8];
    *reinterpret_cast<float4*>(&av[0]) = *reinterpret_cast<const float4*>(rowA);
    *reinterpret_cast<float4*>(&av[4]) = *reinterpret_cast<const float4*>(rowA + 4);
    *reinterpret_cast<float4*>(&bv[0]) = *reinterpret_cast<const float4*>(rowB);
    *reinterpret_cast<float4*>(&bv[4]) = *reinterpret_cast<const float4*>(rowB + 4);

    float sA = 0.f, sB = 0.f;
    #pragma unroll
    for (int e = 0; e < 8; ++e) { sA += av[e]; sB += bv[e]; }
    sA += __shfl_xor(sA, 1, 64); sA += __shfl_xor(sA, 2, 64); sA += __shfl_xor(sA, 4, 64);
    sB += __shfl_xor(sB, 1, 64); sB += __shfl_xor(sB, 2, 64); sB += __shfl_xor(sB, 4, 64);
    if (poct == 0) {
        gpart[((size_t)(b * 256 + c0 + 2 * cpair)) * 64 + pchunk] = sA;
        gpart[((size_t)(b * 256 + c0 + 2 * cpair + 1)) * 64 + pchunk] = sB;
    }

    const int s = cpair >> 2, w = cpair & 3;
    #pragma unroll
    for (int e = 0; e < 8; ++e) {
        int p = poct * 8 + e;
        unsigned int u = (unsigned int)(unsigned short)f2bf(av[e]) |
                         ((unsigned int)(unsigned short)f2bf(bv[e]) << 16);
        tile[p * 32 + ((s ^ poct) << 2) + w] = u;
    }
    __syncthreads();

    const int so = tid & 7;
    #pragma unroll
    for (int h = 0; h < 2; ++h) {
        int p = (tid >> 3) + h * 32;
        int sp = so ^ ((p >> 3) & 7);
        uint4 v = *reinterpret_cast<const uint4*>(&tile[p * 32 + sp * 4]);
        *reinterpret_cast<uint4*>(xt + ((size_t)b * 4096 + p0 + p) * 256 + c0 + so * 8) = v;
    }
}

// ---------------- K2: g-reduce, s, t, q; blocks 32..47 convert w2l->bf16 ----------------
__global__ __launch_bounds__(256) void prep_kernel(
    const float* __restrict__ gpart, const float* __restrict__ w1l,
    const float* __restrict__ w1g1, const float* __restrict__ w1g2,
    const float* __restrict__ w2l, const float* __restrict__ w2g,
    float* __restrict__ s_out, float* __restrict__ t_out,
    float* __restrict__ q_out, short* __restrict__ w2l_bf) {
    int b = blockIdx.x;
    int tid = threadIdx.x;
    if (b >= 32) {
        int seg = b - 32;
        const float* src = w2l + seg * 4096;
        short* dst = w2l_bf + seg * 4096;
        #pragma unroll
        for (int it = 0; it < 4; ++it) {
            float4 v = *reinterpret_cast<const float4*>(src + it * 1024 + tid * 4);
            short4 o;
            o.x = f2bf(v.x); o.y = f2bf(v.y); o.z = f2bf(v.z); o.w = f2bf(v.w);
            *reinterpret_cast<short4*>(dst + it * 1024 + tid * 4) = o;
        }
        return;
    }
    __shared__ float gs[256];
    __shared__ float zs[8];
    __shared__ float ss[256];
    __shared__ float red[4];
    {
        const float4* gp = reinterpret_cast<const float4*>(gpart + (size_t)(b * 256 + tid) * 64);
        float acc = 0.f;
        #pragma unroll
        for (int j = 0; j < 16; ++j) { float4 v = gp[j]; acc += v.x + v.y + v.z + v.w; }
        gs[tid] = acc * (1.0f / 4096.0f);
    }
    __syncthreads();
    if (tid < 8) {
        float z = 0.f;
        for (int i = 0; i < 32; ++i) z += gs[tid * 32 + i] * w1g1[tid * 32 + i];
        zs[tid] = z;
    }
    __syncthreads();
    int grp = tid >> 5, o = tid & 31;
    float local = 0.f;
    #pragma unroll 4
    for (int i = 0; i < 32; ++i) local += gs[grp * 32 + i] * w1l[grp * 1024 + o * 32 + i];
    float glob = 0.f;
    #pragma unroll
    for (int gg = 0; gg < 8; ++gg) glob += zs[gg] * w1g2[tid * 8 + gg];
    float sv = 1.0f / (1.0f + expf(-(local + glob)));
    ss[tid] = sv;
    s_out[b * 256 + tid] = sv;
    float tv = sv * w2g[tid];
    #pragma unroll
    for (int off = 32; off; off >>= 1) tv += __shfl_down(tv, off, 64);
    if ((tid & 63) == 0) red[tid >> 6] = tv;
    __syncthreads();
    float tb = red[0] + red[1] + red[2] + red[3];
    if (tid == 0) t_out[b] = tb;
    float v = 0.f;
    for (int o2 = 0; o2 < 256; ++o2) v += ss[o2] * w2l[o2 * 256 + tid];
    q_out[b * 256 + tid] = v * (1.0f / 256.0f) + tb;
}

// ---------------- K3: partial cmap0/xsum over a 64-channel slice (K-split 4) ------------
__global__ __launch_bounds__(256) void cmap0_kernel(const float* __restrict__ x,
                                                    const float* __restrict__ q,
                                                    float* __restrict__ cmap0p,
                                                    float* __restrict__ xsump) {
    const int part = blockIdx.y;           // 0..3 -> channels part*64..+63
    const int b = blockIdx.z;
    const int p = blockIdx.x * 1024 + threadIdx.x * 4;
    __shared__ float qs[64];
    if (threadIdx.x < 64) qs[threadIdx.x] = q[b * 256 + part * 64 + threadIdx.x];
    __syncthreads();
    const float* xb = x + ((size_t)(b * 256 + part * 64)) * 4096 + p;
    f32x4 a = {0.f, 0.f, 0.f, 0.f}, sm = {0.f, 0.f, 0.f, 0.f};
    #pragma unroll 8
    for (int i = 0; i < 64; ++i) {
        f32x4 v = *reinterpret_cast<const f32x4*>(xb + (size_t)i * 4096);
        a += qs[i] * v;
        sm += v;
    }
    *reinterpret_cast<f32x4*>(cmap0p + ((size_t)(part * 32 + b)) * 4096 + p) = a;
    *reinterpret_cast<f32x4*>(xsump  + ((size_t)(part * 32 + b)) * 4096 + p) = sm;
}

// ---------------- K4: sum partials -> conv3x3 -> sigmoid -> conv3x3 ----------
__global__ __launch_bounds__(256) void convs_kernel(const float* __restrict__ cmap0p,
                                                    const float* __restrict__ w9a,
                                                    const float* __restrict__ w9b,
                                                    float* __restrict__ out) {
    int b = blockIdx.x;
    int tid = threadIdx.x;
    __shared__ float img[4096];
    __shared__ float mid[4096];
    float wa[9], wb[9];
    #pragma unroll
    for (int i = 0; i < 9; ++i) { wa[i] = w9a[i]; wb[i] = w9b[i]; }
    {
        #pragma unroll
        for (int it = 0; it < 4; ++it) {
            int idx = it * 256 + tid;     // float4 index into 4096 floats
            f32x4 v = {0.f, 0.f, 0.f, 0.f};
            #pragma unroll
            for (int part = 0; part < 4; ++part)
                v += *reinterpret_cast<const f32x4*>(cmap0p + ((size_t)(part * 32 + b)) * 4096 + idx * 4);
            *reinterpret_cast<f32x4*>(&img[idx * 4]) = v;
        }
    }
    __syncthreads();
    #pragma unroll
    for (int it = 0; it < 16; ++it) {
        int pix = it * 256 + tid;
        int y = pix >> 6, x0 = pix & 63;
        float acc = 0.f;
        #pragma unroll
        for (int dy = -1; dy <= 1; ++dy)
            #pragma unroll
            for (int dx = -1; dx <= 1; ++dx) {
                int yy = y + dy, xx = x0 + dx;
                if (yy >= 0 && yy < 64 && xx >= 0 && xx < 64)
                    acc += img[yy * 64 + xx] * wa[(dy + 1) * 3 + (dx + 1)];
            }
        mid[pix] = 1.0f / (1.0f + expf(-acc));
    }
    __syncthreads();
    #pragma unroll
    for (int it = 0; it < 16; ++it) {
        int pix = it * 256 + tid;
        int y = pix >> 6, x0 = pix & 63;
        float acc = 0.f;
        #pragma unroll
        for (int dy = -1; dy <= 1; ++dy)
            #pragma unroll
            for (int dx = -1; dx <= 1; ++dx) {
                int yy = y + dy, xx = x0 + dx;
                if (yy >= 0 && yy < 64 && xx >= 0 && xx < 64)
                    acc += mid[yy * 64 + xx] * wb[(dy + 1) * 3 + (dx + 1)];
            }
        out[(size_t)b * 4096 + pix] = acc;
    }
}

// ---------------- K5: GEMM + epilogue. BM=256(all o) x BN=64, BK=64, 8 waves. -----------
__global__ __launch_bounds__(512) void gemm_epi_kernel(
    const short* __restrict__ xt, const short* __restrict__ w2l_bf,
    const float* __restrict__ s, const float* __restrict__ t,
    const float* __restrict__ xsump, const float* __restrict__ cmap,
    float* __restrict__ out) {
    const int b  = blockIdx.z;
    const int p0 = blockIdx.x * 64;
    const int tid  = threadIdx.x;
    const int lane = tid & 63;
    const int w    = tid >> 6;          // wave 0..7
    const int wm = w >> 1, wn = w & 1;  // 4x2 wave grid: 64 o x 32 p each

    __shared__ short Alds[256 * 64];    // 32 KB
    __shared__ short Xlds[64 * 64];     // 8 KB

    const int sl   = (lane & 7) ^ (lane >> 3);  // pre-swizzled source slot
    const int lrow = lane >> 3;

    f32x4 acc[4][2] = {};

    for (int ks = 0; ks < 256; ks += 64) {
        #pragma unroll
        for (int j = 0; j < 4; ++j) {
            int chunk = w * 4 + j;
            int row = chunk * 8 + lrow;
            gload_lds16(w2l_bf + (size_t)row * 256 + ks + sl * 8,
                        (char*)Alds + chunk * 1024);
        }
        {
            int prow = w * 8 + lrow;
            gload_lds16(xt + ((size_t)b * 4096 + p0 + prow) * 256 + ks + sl * 8,
                        (char*)Xlds + w * 1024);
        }
        __syncthreads();
        #pragma unroll
        for (int kk = 0; kk < 2; ++kk) {
            bf16x8 af[4], bfr[2];
            const int ss = kk * 4 + (lane >> 4);
            #pragma unroll
            for (int m = 0; m < 4; ++m) {
                int o = wm * 64 + m * 16 + (lane & 15);
                af[m] = *reinterpret_cast<const bf16x8*>(
                    (char*)Alds + o * 128 + ((ss ^ (lane & 7)) * 16));
            }
            #pragma unroll
            for (int n = 0; n < 2; ++n) {
                int p = wn * 32 + n * 16 + (lane & 15);
                bfr[n] = *reinterpret_cast<const bf16x8*>(
                    (char*)Xlds + p * 128 + ((ss ^ (lane & 7)) * 16));
            }
            #pragma unroll
            for (int m = 0; m < 4; ++m)
                #pragma unroll
                for (int n = 0; n < 2; ++n)
                    acc[m][n] = __builtin_amdgcn_mfma_f32_16x16x32_bf16(af[m], bfr[n], acc[m][n], 0, 0, 0);
        }
        __syncthreads();
    }
    const float tb = t[b];
    #pragma unroll
    for (int n = 0; n < 2; ++n) {
        int p = p0 + wn * 32 + n * 16 + (lane & 15);
        float xs = 0.f;
        #pragma unroll
        for (int part = 0; part < 4; ++part)
            xs += xsump[((size_t)(part * 32 + b)) * 4096 + p];
        float cm = cmap[b * 4096 + p];
        float txs = tb * xs;
        #pragma unroll
        for (int m = 0; m < 4; ++m) {
            #pragma unroll
            for (int r = 0; r < 4; ++r) {
                int o = wm * 64 + m * 16 + (lane >> 4) * 4 + r;
                float yv = s[b * 256 + o] * acc[m][n][r] + txs;
                out[((size_t)b * 256 + o) * 4096 + p] = yv * cm;
            }
        }
    }
}

extern "C" void kernel_launch(void* const* d_in, const int* in_sizes, int n_in,
                              void* d_out, int out_size, void* d_ws, size_t ws_size,
                              hipStream_t stream) {
    const float* x       = (const float*)d_in[0];
    const float* w1l     = (const float*)d_in[1];
    const float* w1g1    = (const float*)d_in[2];
    const float* w1g2    = (const float*)d_in[3];
    const float* w2l     = (const float*)d_in[4];
    const float* w2g     = (const float*)d_in[5];
    const float* conv1_w = (const float*)d_in[6];
    const float* conv2_w = (const float*)d_in[7];
    float* out = (float*)d_out;

    float* wsf    = (float*)d_ws;
    float* s      = wsf;                        // 8192
    float* t      = wsf + 8192;                 // 64
    float* q      = wsf + 8256;                 // 8192
    float* cmap0p = wsf + 16448;                // 4*32*4096 = 524288
    float* xsump  = wsf + 540736;               // 524288
    float* cmap   = wsf + 1065024;              // 131072
    float* gpart  = wsf + 1196096;              // 524288
    short* w2l_bf = (short*)(wsf + 1720384);    // 65536 shorts
    short* xt     = (short*)(wsf + 1753152);    // 33554432 shorts (64 MiB)

    transpose_kernel<<<dim3(64, 4, 32), 256, 0, stream>>>(x, xt, gpart);
    prep_kernel<<<48, 256, 0, stream>>>(gpart, w1l, w1g1, w1g2, w2l, w2g, s, t, q, w2l_bf);
    cmap0_kernel<<<dim3(4, 4, 32), 256, 0, stream>>>(x, q, cmap0p, xsump);
    convs_kernel<<<32, 256, 0, stream>>>(cmap0p, conv1_w, conv2_w, cmap);
    gemm_epi_kernel<<<dim3(64, 1, 32), 512, 0, stream>>>(xt, w2l_bf, s, t, xsump, cmap, out);
}

// Round 4
// 129.559 us; speedup vs baseline: 1.2076x; 1.0956x over previous
//
#include <hip/hip_runtime.h>
#include <hip/hip_bf16.h>

typedef float  f32x4  __attribute__((ext_vector_type(4)));
typedef short  bf16x8 __attribute__((ext_vector_type(8)));

__device__ __forceinline__ short f2bf(float f) {
    union { __hip_bfloat16 h; short s; } u;
    u.h = __float2bfloat16(f);
    return u.s;
}

__device__ __forceinline__ void gload_lds16(const void* g, void* l) {
    __builtin_amdgcn_global_load_lds(
        (const __attribute__((address_space(1))) unsigned int*)g,
        (__attribute__((address_space(3))) unsigned int*)l, 16, 0, 0);
}

// ---------------- K1: transpose x -> xt bf16 [b][p][c]; partial g sums; partial xsum ----
// Block tile: 64 c x 64 p. Thread owns a c-PAIR x 8 p.
__global__ __launch_bounds__(256) void transpose_kernel(const float* __restrict__ x,
                                                        short* __restrict__ xt,
                                                        float* __restrict__ gpart,
                                                        float* __restrict__ xsump) {
    const int pchunk = blockIdx.x;
    const int cchunk = blockIdx.y;
    const int c0 = cchunk * 64;
    const int b  = blockIdx.z;
    const int tid = threadIdx.x;
    const int cpair = tid >> 3;      // 0..31 -> c = c0 + 2*cpair + {0,1}
    const int poct  = tid & 7;       // p = poct*8 + e
    const int p0 = pchunk * 64;

    __shared__ unsigned int tile[64 * 32];   // 8 KB

    const float* rowA = x + ((size_t)(b * 256 + c0 + 2 * cpair)) * 4096 + p0 + poct * 8;
    const float* rowB = rowA + 4096;
    float av[8], bv[8];
    *reinterpret_cast<float4*>(&av[0]) = *reinterpret_cast<const float4*>(rowA);
    *reinterpret_cast<float4*>(&av[4]) = *reinterpret_cast<const float4*>(rowA + 4);
    *reinterpret_cast<float4*>(&bv[0]) = *reinterpret_cast<const float4*>(rowB);
    *reinterpret_cast<float4*>(&bv[4]) = *reinterpret_cast<const float4*>(rowB + 4);

    // per-channel sums for g
    float sA = 0.f, sB = 0.f;
    #pragma unroll
    for (int e = 0; e < 8; ++e) { sA += av[e]; sB += bv[e]; }
    sA += __shfl_xor(sA, 1, 64); sA += __shfl_xor(sA, 2, 64); sA += __shfl_xor(sA, 4, 64);
    sB += __shfl_xor(sB, 1, 64); sB += __shfl_xor(sB, 2, 64); sB += __shfl_xor(sB, 4, 64);
    if (poct == 0) {
        gpart[((size_t)(b * 256 + c0 + 2 * cpair)) * 64 + pchunk] = sA;
        gpart[((size_t)(b * 256 + c0 + 2 * cpair + 1)) * 64 + pchunk] = sB;
    }

    // per-p xsum partial over this wave's 16 channels (reduce over lane bits 3..5)
    float xs[8];
    #pragma unroll
    for (int e = 0; e < 8; ++e) {
        float v = av[e] + bv[e];
        v += __shfl_xor(v, 8, 64);
        v += __shfl_xor(v, 16, 64);
        v += __shfl_xor(v, 32, 64);
        xs[e] = v;
    }
    if ((tid & 56) == 0) {  // lane>>3 == 0 in each wave
        int wv = tid >> 6;
        float* dst = xsump + ((size_t)((cchunk * 4 + wv) * 32 + b)) * 4096 + p0 + poct * 8;
        *reinterpret_cast<f32x4*>(dst)     = *reinterpret_cast<f32x4*>(&xs[0]);
        *reinterpret_cast<f32x4*>(dst + 4) = *reinterpret_cast<f32x4*>(&xs[4]);
    }

    const int s = cpair >> 2, w = cpair & 3;
    #pragma unroll
    for (int e = 0; e < 8; ++e) {
        int p = poct * 8 + e;
        unsigned int u = (unsigned int)(unsigned short)f2bf(av[e]) |
                         ((unsigned int)(unsigned short)f2bf(bv[e]) << 16);
        tile[p * 32 + ((s ^ poct) << 2) + w] = u;
    }
    __syncthreads();

    const int so = tid & 7;
    #pragma unroll
    for (int h = 0; h < 2; ++h) {
        int p = (tid >> 3) + h * 32;
        int sp = so ^ ((p >> 3) & 7);
        uint4 v = *reinterpret_cast<const uint4*>(&tile[p * 32 + sp * 4]);
        *reinterpret_cast<uint4*>(xt + ((size_t)b * 4096 + p0 + p) * 256 + c0 + so * 8) = v;
    }
}

// ---------------- K2: g-reduce, s, t, vq; blocks 32..47 convert w2l->bf16 ----------------
__global__ __launch_bounds__(256) void prep_kernel(
    const float* __restrict__ gpart, const float* __restrict__ w1l,
    const float* __restrict__ w1g1, const float* __restrict__ w1g2,
    const float* __restrict__ w2l, const float* __restrict__ w2g,
    float* __restrict__ s_out, float* __restrict__ t_out,
    float* __restrict__ vq_out, short* __restrict__ w2l_bf) {
    int b = blockIdx.x;
    int tid = threadIdx.x;
    if (b >= 32) {
        int seg = b - 32;
        const float* src = w2l + seg * 4096;
        short* dst = w2l_bf + seg * 4096;
        #pragma unroll
        for (int it = 0; it < 4; ++it) {
            float4 v = *reinterpret_cast<const float4*>(src + it * 1024 + tid * 4);
            short4 o;
            o.x = f2bf(v.x); o.y = f2bf(v.y); o.z = f2bf(v.z); o.w = f2bf(v.w);
            *reinterpret_cast<short4*>(dst + it * 1024 + tid * 4) = o;
        }
        return;
    }
    __shared__ float gs[256];
    __shared__ float zs[8];
    __shared__ float ss[256];
    __shared__ float red[4];
    {
        const float4* gp = reinterpret_cast<const float4*>(gpart + (size_t)(b * 256 + tid) * 64);
        float acc = 0.f;
        #pragma unroll
        for (int j = 0; j < 16; ++j) { float4 v = gp[j]; acc += v.x + v.y + v.z + v.w; }
        gs[tid] = acc * (1.0f / 4096.0f);
    }
    __syncthreads();
    if (tid < 8) {
        float z = 0.f;
        for (int i = 0; i < 32; ++i) z += gs[tid * 32 + i] * w1g1[tid * 32 + i];
        zs[tid] = z;
    }
    __syncthreads();
    int grp = tid >> 5, o = tid & 31;
    float local = 0.f;
    #pragma unroll 4
    for (int i = 0; i < 32; ++i) local += gs[grp * 32 + i] * w1l[grp * 1024 + o * 32 + i];
    float glob = 0.f;
    #pragma unroll
    for (int gg = 0; gg < 8; ++gg) glob += zs[gg] * w1g2[tid * 8 + gg];
    float sv = 1.0f / (1.0f + expf(-(local + glob)));
    ss[tid] = sv;
    s_out[b * 256 + tid] = sv;
    float tv = sv * w2g[tid];
    #pragma unroll
    for (int off = 32; off; off >>= 1) tv += __shfl_down(tv, off, 64);
    if ((tid & 63) == 0) red[tid >> 6] = tv;
    __syncthreads();
    float tb = red[0] + red[1] + red[2] + red[3];
    if (tid == 0) t_out[b] = tb;
    float v = 0.f;
    for (int o2 = 0; o2 < 256; ++o2) v += ss[o2] * w2l[o2 * 256 + tid];
    vq_out[b * 256 + tid] = v * (1.0f / 256.0f);     // NOTE: t kept separate (exact path)
}

// ---------------- K3: cmap0 = vq·xt(bf16) + t·xsum(exact); txs = t·xsum ----------------
__global__ __launch_bounds__(256) void cmap0_kernel(const short* __restrict__ xt,
                                                    const float* __restrict__ vq,
                                                    const float* __restrict__ t,
                                                    const float* __restrict__ xsump,
                                                    float* __restrict__ cmap0,
                                                    float* __restrict__ txs) {
    const int b = blockIdx.y;
    const int p = blockIdx.x * 256 + threadIdx.x;
    __shared__ float vs[256];
    vs[threadIdx.x] = vq[b * 256 + threadIdx.x];
    __syncthreads();
    const uint4* row = reinterpret_cast<const uint4*>(xt + ((size_t)b * 4096 + p) * 256);
    float acc = 0.f;
    #pragma unroll 8
    for (int it = 0; it < 32; ++it) {
        uint4 u = row[it];
        const unsigned int* uw = reinterpret_cast<const unsigned int*>(&u);
        #pragma unroll
        for (int j = 0; j < 4; ++j) {
            unsigned int wrd = uw[j];
            union { unsigned int u; float f; } lo, hi;
            lo.u = wrd << 16;
            hi.u = wrd & 0xffff0000u;
            acc += lo.f * vs[it * 8 + 2 * j] + hi.f * vs[it * 8 + 2 * j + 1];
        }
    }
    float xs = 0.f;
    #pragma unroll
    for (int part = 0; part < 16; ++part)
        xs += xsump[((size_t)(part * 32 + b)) * 4096 + p];
    float tb = t[b];
    float tx = tb * xs;
    cmap0[b * 4096 + p] = acc + tx;
    txs[b * 4096 + p] = tx;
}

// ---------------- K4: fused conv3x3 -> sigmoid -> conv3x3, 16-row strips ----------------
__global__ __launch_bounds__(256) void convs_kernel(const float* __restrict__ cmap0,
                                                    const float* __restrict__ w9a,
                                                    const float* __restrict__ w9b,
                                                    float* __restrict__ cmap) {
    const int strip = blockIdx.x;       // 0..3
    const int b = blockIdx.y;
    const int tid = threadIdx.x;
    const int r0 = strip * 16;
    const int rlo = (r0 == 0) ? 0 : r0 - 1;
    const int rhi = (r0 + 16 > 63) ? 63 : r0 + 16;
    const int cnt = rhi - rlo + 1;      // 17 or 18

    __shared__ float mid[18 * 64];
    float wa[9], wb[9];
    #pragma unroll
    for (int i = 0; i < 9; ++i) { wa[i] = w9a[i]; wb[i] = w9b[i]; }
    const float* ib = cmap0 + (size_t)b * 4096;

    for (int idx = tid; idx < cnt * 64; idx += 256) {
        int r = rlo + (idx >> 6), cc = idx & 63;
        float acc = 0.f;
        #pragma unroll
        for (int dy = -1; dy <= 1; ++dy)
            #pragma unroll
            for (int dx = -1; dx <= 1; ++dx) {
                int rr = r + dy, xx = cc + dx;
                if (rr >= 0 && rr < 64 && xx >= 0 && xx < 64)
                    acc += ib[rr * 64 + xx] * wa[(dy + 1) * 3 + (dx + 1)];
            }
        mid[idx] = 1.0f / (1.0f + expf(-acc));
    }
    __syncthreads();
    for (int idx = tid; idx < 1024; idx += 256) {
        int r = r0 + (idx >> 6), cc = idx & 63;
        float acc = 0.f;
        #pragma unroll
        for (int dy = -1; dy <= 1; ++dy)
            #pragma unroll
            for (int dx = -1; dx <= 1; ++dx) {
                int rr = r + dy, xx = cc + dx;
                if (rr >= 0 && rr < 64 && xx >= 0 && xx < 64)
                    acc += mid[(rr - rlo) * 64 + xx] * wb[(dy + 1) * 3 + (dx + 1)];
            }
        cmap[(size_t)b * 4096 + r * 64 + cc] = acc;
    }
}

// ---------------- K5: GEMM + epilogue. BM=256(all o) x BN=64, BK=64, 8 waves. -----------
__global__ __launch_bounds__(512) void gemm_epi_kernel(
    const short* __restrict__ xt, const short* __restrict__ w2l_bf,
    const float* __restrict__ s, const float* __restrict__ txs,
    const float* __restrict__ cmap, float* __restrict__ out) {
    const int b  = blockIdx.z;
    const int p0 = blockIdx.x * 64;
    const int tid  = threadIdx.x;
    const int lane = tid & 63;
    const int w    = tid >> 6;          // wave 0..7
    const int wm = w >> 1, wn = w & 1;  // 4x2 wave grid: 64 o x 32 p each

    __shared__ short Alds[256 * 64];    // 32 KB
    __shared__ short Xlds[64 * 64];     // 8 KB

    const int sl   = (lane & 7) ^ (lane >> 3);  // pre-swizzled source slot
    const int lrow = lane >> 3;

    f32x4 acc[4][2] = {};

    for (int ks = 0; ks < 256; ks += 64) {
        #pragma unroll
        for (int j = 0; j < 4; ++j) {
            int chunk = w * 4 + j;
            int row = chunk * 8 + lrow;
            gload_lds16(w2l_bf + (size_t)row * 256 + ks + sl * 8,
                        (char*)Alds + chunk * 1024);
        }
        {
            int prow = w * 8 + lrow;
            gload_lds16(xt + ((size_t)b * 4096 + p0 + prow) * 256 + ks + sl * 8,
                        (char*)Xlds + w * 1024);
        }
        __syncthreads();
        #pragma unroll
        for (int kk = 0; kk < 2; ++kk) {
            bf16x8 af[4], bfr[2];
            const int ss = kk * 4 + (lane >> 4);
            #pragma unroll
            for (int m = 0; m < 4; ++m) {
                int o = wm * 64 + m * 16 + (lane & 15);
                af[m] = *reinterpret_cast<const bf16x8*>(
                    (char*)Alds + o * 128 + ((ss ^ (lane & 7)) * 16));
            }
            #pragma unroll
            for (int n = 0; n < 2; ++n) {
                int p = wn * 32 + n * 16 + (lane & 15);
                bfr[n] = *reinterpret_cast<const bf16x8*>(
                    (char*)Xlds + p * 128 + ((ss ^ (lane & 7)) * 16));
            }
            #pragma unroll
            for (int m = 0; m < 4; ++m)
                #pragma unroll
                for (int n = 0; n < 2; ++n)
                    acc[m][n] = __builtin_amdgcn_mfma_f32_16x16x32_bf16(af[m], bfr[n], acc[m][n], 0, 0, 0);
        }
        __syncthreads();
    }
    #pragma unroll
    for (int n = 0; n < 2; ++n) {
        int p = p0 + wn * 32 + n * 16 + (lane & 15);
        float tx = txs[b * 4096 + p];
        float cm = cmap[b * 4096 + p];
        #pragma unroll
        for (int m = 0; m < 4; ++m) {
            #pragma unroll
            for (int r = 0; r < 4; ++r) {
                int o = wm * 64 + m * 16 + (lane >> 4) * 4 + r;
                float yv = s[b * 256 + o] * acc[m][n][r] + tx;
                out[((size_t)b * 256 + o) * 4096 + p] = yv * cm;
            }
        }
    }
}

extern "C" void kernel_launch(void* const* d_in, const int* in_sizes, int n_in,
                              void* d_out, int out_size, void* d_ws, size_t ws_size,
                              hipStream_t stream) {
    const float* x       = (const float*)d_in[0];
    const float* w1l     = (const float*)d_in[1];
    const float* w1g1    = (const float*)d_in[2];
    const float* w1g2    = (const float*)d_in[3];
    const float* w2l     = (const float*)d_in[4];
    const float* w2g     = (const float*)d_in[5];
    const float* conv1_w = (const float*)d_in[6];
    const float* conv2_w = (const float*)d_in[7];
    float* out = (float*)d_out;

    float* wsf    = (float*)d_ws;
    float* s      = wsf;                        // 8192
    float* t      = wsf + 8192;                 // 64
    float* vq     = wsf + 8256;                 // 8192
    float* cmap0  = wsf + 16448;                // 131072
    float* txs    = wsf + 147520;               // 131072
    float* cmap   = wsf + 278592;               // 131072
    float* gpart  = wsf + 409664;               // 524288
    float* xsump  = wsf + 933952;               // 16*32*4096 = 2097152
    short* w2l_bf = (short*)(wsf + 3031104);    // 65536 shorts
    short* xt     = (short*)(wsf + 3063872);    // 33554432 shorts (64 MiB)

    transpose_kernel<<<dim3(64, 4, 32), 256, 0, stream>>>(x, xt, gpart, xsump);
    prep_kernel<<<48, 256, 0, stream>>>(gpart, w1l, w1g1, w1g2, w2l, w2g, s, t, vq, w2l_bf);
    cmap0_kernel<<<dim3(16, 32), 256, 0, stream>>>(xt, vq, t, xsump, cmap0, txs);
    convs_kernel<<<dim3(4, 32), 256, 0, stream>>>(cmap0, conv1_w, conv2_w, cmap);
    gemm_epi_kernel<<<dim3(64, 1, 32), 512, 0, stream>>>(xt, w2l_bf, s, txs, cmap, out);
}